// Round 1
// 68.665 us; speedup vs baseline: 1.0633x; 1.0633x over previous
//
#include <hip/hip_runtime.h>

#define BB 4
#define MM 128
#define LL 512
#define DD 768
#define NEGF (-1e30f)

struct F3 { float x, y, z; };

// Latency-bound fix vs previous version:
//  - 1024-thread blocks (16 waves/CU = 4 waves/SIMD) instead of 512 (2/SIMD):
//    2x TLP for cold-miss latency hiding. Grid stays 256 = 1 block/CU.
//  - Register staging shrunk from 2x32 rows (192 VGPR, un-allocatable at the
//    128-VGPR cap -> compiler serialized loads, MLP~2) to ping-pong 2x8 rows
//    (48 VGPR): loads for batch k+2 issue right after compute of batch k,
//    batch compute (~700 cy) > L2 latency (~400 cy) -> pipelined by structure.
//  - Each wave owns 32 rows; one ballot covers 2 mentions (lanes 0..31 = m,
//    lanes 32..63 = m+1).
// Arithmetic identical to reference: (h + {0,-1e30}) then max => absmax 0.
__global__ __launch_bounds__(1024, 4) void mention_max_kernel(
    const float* __restrict__ h, const int* __restrict__ mask,
    float* __restrict__ out)
{
    const int lane = threadIdx.x & 63;
    const int wave = threadIdx.x >> 6;   // 0..15
    const int dch  = blockIdx.x;         // 0..3
    const int mch  = blockIdx.y;         // 0..15
    const int b    = blockIdx.z;         // 0..3

    const int d0 = dch * 192 + lane * 3;
    const int m0 = mch * 8;
    const int l0 = wave * 32;

    // 1) mask loads first (oldest vmcnt slots -> ballots don't wait on h).
    //    lane<32 reads mention m0+2p rows l0..l0+31, lane>=32 reads m0+2p+1.
    const int half = lane >> 5;
    const int lrow = lane & 31;
    const int* mp = mask + ((size_t)(b * MM + m0)) * LL + l0 + lrow;
    int mv0 = mp[(0 + half) * LL];
    int mv1 = mp[(2 + half) * LL];
    int mv2 = mp[(4 + half) * LL];
    int mv3 = mp[(6 + half) * LL];

    // 2) first h batch in flight while ballots wait on mask loads only.
    const F3* hp = (const F3*)(h + ((size_t)(b * LL + l0)) * DD + d0);
    F3 ra[8], rb[8];
#pragma unroll
    for (int i = 0; i < 8; ++i) ra[i] = hp[(size_t)i * (DD / 3)];

    unsigned wbits[8];
    { unsigned long long bl = __ballot(mv0 != 0); wbits[0] = (unsigned)bl; wbits[1] = (unsigned)(bl >> 32); }
    { unsigned long long bl = __ballot(mv1 != 0); wbits[2] = (unsigned)bl; wbits[3] = (unsigned)(bl >> 32); }
    { unsigned long long bl = __ballot(mv2 != 0); wbits[4] = (unsigned)bl; wbits[5] = (unsigned)(bl >> 32); }
    { unsigned long long bl = __ballot(mv3 != 0); wbits[6] = (unsigned)bl; wbits[7] = (unsigned)(bl >> 32); }

#pragma unroll
    for (int i = 0; i < 8; ++i) rb[i] = hp[(size_t)(i + 8) * (DD / 3)];

    F3 acc[8];
#pragma unroll
    for (int m = 0; m < 8; ++m) { acc[m].x = NEGF; acc[m].y = NEGF; acc[m].z = NEGF; }

    // Compute one 8-row batch across all 8 mentions. IB = bit base in wbits.
#define COMPUTE_BATCH(BUF, IB)                                                 \
    do {                                                                       \
        _Pragma("unroll")                                                      \
        for (int m = 0; m < 8; ++m) {                                          \
            const unsigned w32 = wbits[m] >> (IB);                             \
            F3 a = acc[m];                                                     \
            _Pragma("unroll")                                                  \
            for (int i = 0; i < 8; i += 2) {                                   \
                const float ad0 = ((w32 >> i) & 1u) ? 0.0f : NEGF;             \
                const float ad1 = ((w32 >> (i + 1)) & 1u) ? 0.0f : NEGF;       \
                a.x = fmaxf(fmaxf(BUF[i].x + ad0, BUF[i + 1].x + ad1), a.x);   \
                a.y = fmaxf(fmaxf(BUF[i].y + ad0, BUF[i + 1].y + ad1), a.y);   \
                a.z = fmaxf(fmaxf(BUF[i].z + ad0, BUF[i + 1].z + ad1), a.z);   \
            }                                                                  \
            acc[m] = a;                                                        \
        }                                                                      \
    } while (0)

    // 3) ping-pong: compute batch k while batch k+1 is in flight; issue
    //    batch k+2 immediately after batch k's compute frees its buffer.
    COMPUTE_BATCH(ra, 0);
#pragma unroll
    for (int i = 0; i < 8; ++i) ra[i] = hp[(size_t)(i + 16) * (DD / 3)];
    COMPUTE_BATCH(rb, 8);
#pragma unroll
    for (int i = 0; i < 8; ++i) rb[i] = hp[(size_t)(i + 24) * (DD / 3)];
    COMPUTE_BATCH(ra, 16);
    COMPUTE_BATCH(rb, 24);
#undef COMPUTE_BATCH

    // 4) two-stage 16-wave reduce in 48 KB LDS (component-split, conflict-free).
    __shared__ float red[8][8][3][64];
    if (wave >= 8) {
#pragma unroll
        for (int m = 0; m < 8; ++m) {
            red[wave - 8][m][0][lane] = acc[m].x;
            red[wave - 8][m][1][lane] = acc[m].y;
            red[wave - 8][m][2][lane] = acc[m].z;
        }
    }
    __syncthreads();
    if (wave < 8) {
        // merge upper-half partial, then deposit merged value in place.
#pragma unroll
        for (int m = 0; m < 8; ++m) {
            float vx = fmaxf(acc[m].x, red[wave][m][0][lane]);
            float vy = fmaxf(acc[m].y, red[wave][m][1][lane]);
            float vz = fmaxf(acc[m].z, red[wave][m][2][lane]);
            red[wave][m][0][lane] = vx;
            red[wave][m][1][lane] = vy;
            red[wave][m][2][lane] = vz;
        }
    }
    __syncthreads();

    // 5) final: 512 threads -> 8 m x 64 lanes, one float3 output each.
    if (threadIdx.x < 512) {
        const int m  = (int)(threadIdx.x >> 6);
        const int ln = (int)(threadIdx.x & 63);
        float vx = red[0][m][0][ln];
        float vy = red[0][m][1][ln];
        float vz = red[0][m][2][ln];
#pragma unroll
        for (int w = 1; w < 8; ++w) {
            vx = fmaxf(vx, red[w][m][0][ln]);
            vy = fmaxf(vy, red[w][m][1][ln]);
            vz = fmaxf(vz, red[w][m][2][ln]);
        }
        float* op = out + ((size_t)(b * MM + m0 + m)) * DD + dch * 192 + ln * 3;
        op[0] = vx;
        op[1] = vy;
        op[2] = vz;
    }
}

extern "C" void kernel_launch(void* const* d_in, const int* in_sizes, int n_in,
                              void* d_out, int out_size, void* d_ws, size_t ws_size,
                              hipStream_t stream) {
    const float* h    = (const float*)d_in[0];
    const int*   mask = (const int*)d_in[1];
    float*       out  = (float*)d_out;
    dim3 grid(DD / 192, MM / 8, BB);
    mention_max_kernel<<<grid, dim3(1024), 0, stream>>>(h, mask, out);
}